// Round 7
// baseline (1089.430 us; speedup 1.0000x reference)
//
#include <hip/hip_runtime.h>
#include <hip/hip_bf16.h>

// B=16, S=2048, D=1024, OUT=1024.
// attn[b,s] = softmax_s( sum_o v[o]*relu( [hidden|c_t|enc].W[o,:] + bias[o] ) )
// c_t hoisted to cbias[b,o]; main GEMM: A[32768,2048](bf16) x W_he[1024,2048](bf16).
// R6 gemm (TM=256,TN=128,BK=64, XOR swizzle, 0 conflicts, ~870 TF) frozen.
// R7: single fused kernel; grid 512x512thr co-resident (launch_bounds(512,4) => >=2
// blocks/CU => capacity >= 512). Per-mtile flag release overlaps A-conv with gemm.

typedef __attribute__((ext_vector_type(8))) short short8;
typedef __attribute__((ext_vector_type(4))) float f32x4;
typedef __attribute__((ext_vector_type(8))) unsigned short ushort8v;
typedef __attribute__((ext_vector_type(4))) unsigned short ushort4v;

#define NB 16
#define NS 2048
#define ND 1024
#define NOUT 1024
#define NM (NB * NS)   // 32768 rows
#define KHE 2048       // hidden+encoder K
#define TM 256
#define TN 128
#define BK 64
#define NROWS (TM + TN)   // 384 staged rows/slab

__device__ __forceinline__ unsigned short bf16_rne(float x) {
    unsigned int u = __float_as_uint(x);
    unsigned int r = (u + 0x7fffu + ((u >> 16) & 1u)) >> 16;
    return (unsigned short)r;
}

__device__ __forceinline__ void gload_lds16(const unsigned short* g, unsigned short* l) {
    __builtin_amdgcn_global_load_lds(
        (const __attribute__((address_space(1))) void*)g,
        (__attribute__((address_space(3))) void*)l, 16, 0, 0);
}

__device__ __forceinline__ void cvt16(const float* src, unsigned short* dst) {
    float4 f0 = ((const float4*)src)[0];
    float4 f1 = ((const float4*)src)[1];
    float4 f2 = ((const float4*)src)[2];
    float4 f3 = ((const float4*)src)[3];
    ushort8v h0, h1;
    h0[0] = bf16_rne(f0.x); h0[1] = bf16_rne(f0.y); h0[2] = bf16_rne(f0.z); h0[3] = bf16_rne(f0.w);
    h0[4] = bf16_rne(f1.x); h0[5] = bf16_rne(f1.y); h0[6] = bf16_rne(f1.z); h0[7] = bf16_rne(f1.w);
    h1[0] = bf16_rne(f2.x); h1[1] = bf16_rne(f2.y); h1[2] = bf16_rne(f2.z); h1[3] = bf16_rne(f2.w);
    h1[4] = bf16_rne(f3.x); h1[5] = bf16_rne(f3.y); h1[6] = bf16_rne(f3.z); h1[7] = bf16_rne(f3.w);
    *(ushort8v*)dst = h0;
    *(ushort8v*)(dst + 8) = h1;
}

// ===================== fused: conv + flag-sync + gemm + softmax ==========================
// ctr[0]=W-ready (target 64), ctr[1]=gemm-done (target 512), ctr[2+mt]=A-group (target 4)
__global__ __launch_bounds__(512, 4) void fused_k(const float* __restrict__ hidden,
                                                  const float* __restrict__ enc,
                                                  const float* __restrict__ c_t,
                                                  const float* __restrict__ W,
                                                  const float* __restrict__ bias,
                                                  const float* __restrict__ v,
                                                  unsigned int* __restrict__ ctr,
                                                  unsigned short* __restrict__ Abf,
                                                  unsigned short* __restrict__ Wbf,
                                                  float* __restrict__ cbias,
                                                  float* __restrict__ logits,
                                                  float* __restrict__ out) {
    __shared__ unsigned short Ls[NROWS * BK] __attribute__((aligned(16)));  // 48 KiB
    __shared__ float rowsum[2][TM];
    __shared__ float cb_s[TN];
    __shared__ float v_s[TN];

    const int tid = threadIdx.x;
    const int bid = blockIdx.x;
    const int mt = bid >> 2;     // 128 mtile groups
    const int sub = bid & 3;     // 4 blocks per group

    // ---------- phase W (blocks 0..63): Wbf rows [bid*16,+16) + cbias for those o's ------
    if (bid < 64) {
        #pragma unroll
        for (int c = 0; c < 4; ++c) {
            int idx = tid + c * 512;             // 2048 chunks of 16 over 16 o-rows
            int o = bid * 16 + (idx >> 7);       // 128 chunks per o-row
            int k = (idx & 127) * 16;
            int off = (k < ND) ? k : (k + ND);   // skip c_t columns
            cvt16(W + (size_t)o * 3072 + off, Wbf + (size_t)o * KHE + k);
        }
        const int wv = tid >> 6, lane = tid & 63;
        #pragma unroll
        for (int u = 0; u < 2; ++u) {
            int o = bid * 16 + wv * 2 + u;
            const float* wrow = W + (size_t)o * 3072 + ND;
            float wr[16];
            #pragma unroll
            for (int j = 0; j < 16; ++j) wr[j] = wrow[lane + j * 64];
            float bo = bias[o];
            for (int b = 0; b < NB; ++b) {
                const float* cc = c_t + (size_t)b * ND;
                float s = 0.f;
                #pragma unroll
                for (int j = 0; j < 16; ++j) s = fmaf(cc[lane + j * 64], wr[j], s);
                #pragma unroll
                for (int m = 1; m < 64; m <<= 1) s += __shfl_xor(s, m);
                if (lane == 0) cbias[b * NOUT + o] = s + bo;
            }
        }
        __syncthreads();
        __threadfence();
        if (tid == 0)
            __hip_atomic_fetch_add(&ctr[0], 1u, __ATOMIC_RELEASE, __HIP_MEMORY_SCOPE_AGENT);
    }

    // ---------- phase A: convert rows [mt*256,+256), cols [sub*512,+512) ------------------
    {
        const float* base = (sub < 2) ? hidden : enc;
        const int k0 = (sub & 1) * 512;          // col offset within source tensor
        const int kd = sub * 512;                // col offset within Abf
        #pragma unroll
        for (int c = 0; c < 16; ++c) {
            int idx = tid + c * 512;             // 8192 chunks of 16
            int r = idx >> 5;                    // 32 chunks per row
            int kc = (idx & 31) * 16;
            cvt16(base + (size_t)(mt * 256 + r) * ND + k0 + kc,
                  Abf + (size_t)(mt * 256 + r) * KHE + kd + kc);
        }
        __syncthreads();
        __threadfence();
        if (tid == 0)
            __hip_atomic_fetch_add(&ctr[2 + mt], 1u, __ATOMIC_RELEASE, __HIP_MEMORY_SCOPE_AGENT);
    }

    // ---------- wait: W ready + own A group complete -------------------------------------
    if (tid == 0) {
        while (__hip_atomic_load(&ctr[0], __ATOMIC_ACQUIRE, __HIP_MEMORY_SCOPE_AGENT) < 64u)
            __builtin_amdgcn_s_sleep(16);
        while (__hip_atomic_load(&ctr[2 + mt], __ATOMIC_ACQUIRE, __HIP_MEMORY_SCOPE_AGENT) < 4u)
            __builtin_amdgcn_s_sleep(16);
    }
    __syncthreads();
    __threadfence();

    // ---------- gemm: R6 structure, 2 ntiles sequentially --------------------------------
    const int m0 = mt * TM;
    const int batch = m0 >> 11;
    const int wid = tid >> 6;
    const int lane = tid & 63;
    const int wm = (wid & 3) * 64;
    const int wn = (wid >> 2) * 64;
    const int srow = lane >> 3;
    const int schunk = (lane & 7) ^ srow;

    for (int t = 0; t < 2; ++t) {
        const int o0 = (sub * 2 + t) * TN;
        if (tid < TN) {
            cb_s[tid] = cbias[batch * NOUT + o0 + tid];
            v_s[tid] = v[o0 + tid];
        }
        f32x4 acc[4][4] = {};

        for (int kt = 0; kt < KHE; kt += BK) {
            #pragma unroll
            for (int q = 0; q < 6; ++q) {
                const int r0 = wid * 48 + q * 8;
                const unsigned short* src = (r0 < TM)
                    ? (Abf + (size_t)(m0 + r0 + srow) * KHE + kt + schunk * 8)
                    : (Wbf + (size_t)(o0 + r0 - TM + srow) * KHE + kt + schunk * 8);
                gload_lds16(src, Ls + r0 * BK);
            }
            __syncthreads();

            #pragma unroll
            for (int s = 0; s < 2; ++s) {
                const int cbase = s * 4 + (lane >> 4);
                short8 a_frag[4], b_frag[4];
                #pragma unroll
                for (int i = 0; i < 4; ++i) {
                    int row = wm + i * 16 + (lane & 15);
                    a_frag[i] = *(const short8*)(Ls + row * BK + ((cbase ^ (row & 7)) * 8));
                }
                #pragma unroll
                for (int j = 0; j < 4; ++j) {
                    int row = TM + wn + j * 16 + (lane & 15);
                    b_frag[j] = *(const short8*)(Ls + row * BK + ((cbase ^ (row & 7)) * 8));
                }
                #pragma unroll
                for (int i = 0; i < 4; ++i)
                    #pragma unroll
                    for (int j = 0; j < 4; ++j)
                        acc[i][j] = __builtin_amdgcn_mfma_f32_16x16x32_bf16(a_frag[i], b_frag[j],
                                                                            acc[i][j], 0, 0, 0);
            }
            __syncthreads();
        }

        // epilogue: relu(acc+cbias)*v, reduce over this tile's 128 o's.
        // C/D: col = lane&15 (o), row = (lane>>4)*4 + reg (m).  (verified rounds 1-6)
        const int col = lane & 15;
        const int qq = lane >> 4;
        float vv[4], cbv[4];
        #pragma unroll
        for (int j = 0; j < 4; ++j) {
            int oc = wn + j * 16 + col;
            vv[j] = v_s[oc];
            cbv[j] = cb_s[oc];
        }
        #pragma unroll
        for (int i = 0; i < 4; ++i) {
            #pragma unroll
            for (int r = 0; r < 4; ++r) {
                float s = 0.f;
                #pragma unroll
                for (int j = 0; j < 4; ++j) {
                    float e = acc[i][j][r] + cbv[j];
                    e = fmaxf(e, 0.f);
                    s = fmaf(e, vv[j], s);
                }
                s += __shfl_xor(s, 1);
                s += __shfl_xor(s, 2);
                s += __shfl_xor(s, 4);
                s += __shfl_xor(s, 8);
                if (col == 0) rowsum[wid >> 2][wm + i * 16 + qq * 4 + r] = s;
            }
        }
        __syncthreads();
        if (tid < TM) atomicAdd(&logits[m0 + tid], rowsum[0][tid] + rowsum[1][tid]);
    }

    // ---------- done counter; blocks 0..15 run softmax -----------------------------------
    __threadfence();
    __syncthreads();
    if (tid == 0)
        __hip_atomic_fetch_add(&ctr[1], 1u, __ATOMIC_RELEASE, __HIP_MEMORY_SCOPE_AGENT);
    if (bid >= 16) return;

    if (tid == 0) {
        while (__hip_atomic_load(&ctr[1], __ATOMIC_ACQUIRE, __HIP_MEMORY_SCOPE_AGENT) < 512u)
            __builtin_amdgcn_s_sleep(16);
    }
    __syncthreads();
    __threadfence();

    const int wv = tid >> 6, ln = tid & 63;
    float* red = rowsum[0];        // reuse as scratch
    const float* L = logits + (size_t)bid * NS;
    float x[4];
    float mx = -3.4e38f;
    #pragma unroll
    for (int i = 0; i < 4; ++i) {
        x[i] = L[tid + i * 512];
        mx = fmaxf(mx, x[i]);
    }
    #pragma unroll
    for (int m = 1; m < 64; m <<= 1) mx = fmaxf(mx, __shfl_xor(mx, m));
    if (ln == 0) red[wv] = mx;
    __syncthreads();
    mx = red[0];
    #pragma unroll
    for (int w = 1; w < 8; ++w) mx = fmaxf(mx, red[w]);
    float sum = 0.f;
    #pragma unroll
    for (int i = 0; i < 4; ++i) {
        x[i] = expf(x[i] - mx);
        sum += x[i];
    }
    #pragma unroll
    for (int m = 1; m < 64; m <<= 1) sum += __shfl_xor(sum, m);
    if (ln == 0) red[8 + wv] = sum;
    __syncthreads();
    sum = 0.f;
    #pragma unroll
    for (int w = 0; w < 8; ++w) sum += red[8 + w];
    float inv = 1.0f / sum;
    #pragma unroll
    for (int i = 0; i < 4; ++i) out[(size_t)bid * NS + tid + i * 512] = x[i] * inv;
}

// ===================== fallback path (ws too small): R6 pieces ===========================
__global__ __launch_bounds__(256) void wconv_k(const float* __restrict__ W,
                                               unsigned short* __restrict__ Wbf) {
    int idx = blockIdx.x * 256 + threadIdx.x;
    int o = idx >> 9;
    int k = (idx & 511) * 4;
    int off = (k < ND) ? k : (k + ND);
    float4 f = *(const float4*)(W + (size_t)o * 3072 + off);
    ushort4v h;
    h.x = bf16_rne(f.x); h.y = bf16_rne(f.y); h.z = bf16_rne(f.z); h.w = bf16_rne(f.w);
    *(ushort4v*)(Wbf + (size_t)o * KHE + k) = h;
}

__global__ __launch_bounds__(256) void cbias_k(const float* __restrict__ c_t,
                                               const float* __restrict__ W,
                                               const float* __restrict__ bias,
                                               float* __restrict__ cbias) {
    int o = blockIdx.x * 4 + (threadIdx.x >> 6);
    int lane = threadIdx.x & 63;
    const float* w = W + (size_t)o * 3072 + ND;
    float wr[16];
    #pragma unroll
    for (int j = 0; j < 16; ++j) wr[j] = w[lane + j * 64];
    float bo = bias[o];
    for (int b = 0; b < NB; ++b) {
        const float* c = c_t + (size_t)b * ND;
        float s = 0.f;
        #pragma unroll
        for (int j = 0; j < 16; ++j) s = fmaf(c[lane + j * 64], wr[j], s);
        #pragma unroll
        for (int m = 1; m < 64; m <<= 1) s += __shfl_xor(s, m);
        if (lane == 0) cbias[b * NOUT + o] = s + bo;
    }
}

__global__ __launch_bounds__(256) void gemm_att_k(const float* __restrict__ hidden,
                                                  const float* __restrict__ enc,
                                                  const unsigned short* __restrict__ Wbf,
                                                  const float* __restrict__ Wf,
                                                  const float* __restrict__ cbias,
                                                  const float* __restrict__ v,
                                                  float* __restrict__ logits,
                                                  int use_wbf) {
    __shared__ unsigned short As[128 * 32] __attribute__((aligned(16)));
    __shared__ unsigned short Bs[128 * 32] __attribute__((aligned(16)));
    __shared__ float rowsum[2][128];
    __shared__ float cb_s[128];
    __shared__ float v_s[128];

    const int tid = threadIdx.x;
    const int ntile = blockIdx.x & 7;
    const int mtile = blockIdx.x >> 3;
    const int m0 = mtile * 128;
    const int o0 = ntile * 128;
    const int batch = m0 >> 11;

    if (tid < 128) {
        cb_s[tid] = cbias[batch * NOUT + o0 + tid];
        v_s[tid] = v[o0 + tid];
    }

    const int wid = tid >> 6;
    const int lane = tid & 63;
    const int wm = (wid & 1) * 64;
    const int wn = (wid >> 1) * 64;

    f32x4 acc[4][4] = {};

    for (int kt = 0; kt < KHE; kt += 32) {
        const float* Abase = (kt < ND) ? hidden : enc;
        const int aoff = (kt < ND) ? kt : (kt - ND);
        #pragma unroll
        for (int i = 0; i < 4; ++i) {
            int p = tid + i * 256;
            int row = p >> 3, kc = p & 7;
            float4 f = *(const float4*)(Abase + (size_t)(m0 + row) * ND + aoff + kc * 4);
            ushort4v h;
            h.x = bf16_rne(f.x); h.y = bf16_rne(f.y); h.z = bf16_rne(f.z); h.w = bf16_rne(f.w);
            *(ushort4v*)(As + row * 32 + kc * 4) = h;
        }
        if (use_wbf) {
            #pragma unroll
            for (int i = 0; i < 2; ++i) {
                int u = tid + i * 256;
                int ol = u >> 2, kc = u & 3;
                ushort8v w8 = *(const ushort8v*)(Wbf + (size_t)(o0 + ol) * KHE + kt + kc * 8);
                *(ushort8v*)(Bs + ol * 32 + kc * 8) = w8;
            }
        } else {
            const int woff = (kt < ND) ? kt : (kt + ND);
            #pragma unroll
            for (int i = 0; i < 4; ++i) {
                int p = tid + i * 256;
                int row = p >> 3, kc = p & 7;
                float4 f = *(const float4*)(Wf + (size_t)(o0 + row) * 3072 + woff + kc * 4);
                ushort4v h;
                h.x = bf16_rne(f.x); h.y = bf16_rne(f.y); h.z = bf16_rne(f.z); h.w = bf16_rne(f.w);
                *(ushort4v*)(Bs + row * 32 + kc * 4) = h;
            }
        }
        __syncthreads();

        short8 a_frag[4], b_frag[4];
        #pragma unroll
        for (int i = 0; i < 4; ++i)
            a_frag[i] = *(const short8*)(As + (wm + i * 16 + (lane & 15)) * 32 + (lane >> 4) * 8);
        #pragma unroll
        for (int j = 0; j < 4; ++j)
            b_frag[j] = *(const short8*)(Bs + (wn + j * 16 + (lane & 15)) * 32 + (lane >> 4) * 8);
        #pragma unroll
        for (int i = 0; i < 4; ++i)
            #pragma unroll
            for (int j = 0; j < 4; ++j)
                acc[i][j] = __builtin_amdgcn_mfma_f32_16x16x32_bf16(a_frag[i], b_frag[j],
                                                                    acc[i][j], 0, 0, 0);
        __syncthreads();
    }

    const int col = lane & 15;
    const int q = lane >> 4;
    float vv[4], cbv[4];
    #pragma unroll
    for (int j = 0; j < 4; ++j) {
        int oc = wn + j * 16 + col;
        vv[j] = v_s[oc];
        cbv[j] = cb_s[oc];
    }
    #pragma unroll
    for (int i = 0; i < 4; ++i) {
        #pragma unroll
        for (int r = 0; r < 4; ++r) {
            float s = 0.f;
            #pragma unroll
            for (int j = 0; j < 4; ++j) {
                float e = acc[i][j][r] + cbv[j];
                e = fmaxf(e, 0.f);
                s = fmaf(e, vv[j], s);
            }
            s += __shfl_xor(s, 1);
            s += __shfl_xor(s, 2);
            s += __shfl_xor(s, 4);
            s += __shfl_xor(s, 8);
            if (col == 0) rowsum[wid >> 1][wm + i * 16 + q * 4 + r] = s;
        }
    }
    __syncthreads();
    if (tid < 128) atomicAdd(&logits[m0 + tid], rowsum[0][tid] + rowsum[1][tid]);
}

__global__ __launch_bounds__(256) void softmax_k(const float* __restrict__ logits,
                                                 float* __restrict__ out) {
    const int b = blockIdx.x;
    const int tid = threadIdx.x;
    const int lane = tid & 63, wid = tid >> 6;
    __shared__ float redmax[4];
    __shared__ float redsum[4];
    const float* L = logits + (size_t)b * NS;
    float x[8];
    float mx = -3.4e38f;
    #pragma unroll
    for (int i = 0; i < 8; ++i) {
        x[i] = L[tid + i * 256];
        mx = fmaxf(mx, x[i]);
    }
    #pragma unroll
    for (int m = 1; m < 64; m <<= 1) mx = fmaxf(mx, __shfl_xor(mx, m));
    if (lane == 0) redmax[wid] = mx;
    __syncthreads();
    mx = fmaxf(fmaxf(redmax[0], redmax[1]), fmaxf(redmax[2], redmax[3]));
    float sum = 0.f;
    #pragma unroll
    for (int i = 0; i < 8; ++i) {
        x[i] = expf(x[i] - mx);
        sum += x[i];
    }
    #pragma unroll
    for (int m = 1; m < 64; m <<= 1) sum += __shfl_xor(sum, m);
    if (lane == 0) redsum[wid] = sum;
    __syncthreads();
    float inv = 1.0f / (redsum[0] + redsum[1] + redsum[2] + redsum[3]);
    #pragma unroll
    for (int i = 0; i < 8; ++i) out[(size_t)b * NS + tid + i * 256] = x[i] * inv;
}

extern "C" void kernel_launch(void* const* d_in, const int* in_sizes, int n_in,
                              void* d_out, int out_size, void* d_ws, size_t ws_size,
                              hipStream_t stream) {
    const float* hidden = (const float*)d_in[0];
    const float* enc    = (const float*)d_in[1];
    const float* c_t    = (const float*)d_in[2];
    const float* W      = (const float*)d_in[3];
    const float* bias   = (const float*)d_in[4];
    const float* v      = (const float*)d_in[5];
    float* out = (float*)d_out;

    char* ws = (char*)d_ws;
    unsigned int* ctr = (unsigned int*)ws;                      //   4 KiB (counters)
    float* logits = (float*)(ws + 4096);                        // 128 KiB
    float* cbias  = (float*)(ws + 4096 + 131072);               //  64 KiB
    unsigned short* Wbf = (unsigned short*)(ws + 4096 + 196608);        // 4 MiB
    unsigned short* Abf = (unsigned short*)(ws + 4096 + 196608 + 4194304);  // 128 MiB
    const size_t need_wbf = 4096 + 196608 + (size_t)NOUT * KHE * 2;
    const size_t need_abf = need_wbf + (size_t)NM * KHE * 2;

    if (ws_size >= need_abf) {
        hipMemsetAsync(ws, 0, 4096 + 131072, stream);           // counters + logits
        fused_k<<<512, 512, 0, stream>>>(hidden, enc, c_t, W, bias, v,
                                         ctr, Abf, Wbf, cbias, logits, out);
    } else if (ws_size >= need_wbf) {
        hipMemsetAsync(logits, 0, NM * sizeof(float), stream);
        cbias_k<<<NOUT / 4, 256, 0, stream>>>(c_t, W, bias, cbias);
        wconv_k<<<(NOUT * KHE / 4) / 256, 256, 0, stream>>>(W, Wbf);
        gemm_att_k<<<(NM / 128) * (NOUT / 128), 256, 0, stream>>>(hidden, enc, Wbf, W, cbias, v,
                                                                  logits, 1);
        softmax_k<<<NB, 256, 0, stream>>>(logits, out);
    } else {
        hipMemsetAsync(logits, 0, NM * sizeof(float), stream);
        cbias_k<<<NOUT / 4, 256, 0, stream>>>(c_t, W, bias, cbias);
        gemm_att_k<<<(NM / 128) * (NOUT / 128), 256, 0, stream>>>(hidden, enc, Wbf, W, cbias, v,
                                                                  logits, 0);
        softmax_k<<<NB, 256, 0, stream>>>(logits, out);
    }
}